// Round 14
// baseline (268.397 us; speedup 1.0000x reference)
//
#include <hip/hip_runtime.h>

typedef unsigned short u16;
typedef unsigned int u32;
typedef __attribute__((ext_vector_type(4))) float f32x4;
typedef __attribute__((ext_vector_type(8))) short short8;

#define S_LEN 2048
#define BATCH 2
#define HID 2048
#define NH 16
#define HD 128
#define KVR 512
#define TOKENS 4096
// log2(e)/sqrt(HD): folded into Q at GEMM epilogue so attn exp2 takes raw sc
#define QSCALE 0.12751879523243842f

__device__ __forceinline__ u32 f2bf(float f) {
  u32 b = __float_as_uint(f);
  return (b + 0x7FFFu + ((b >> 16) & 1u)) >> 16;
}
__device__ __forceinline__ float bf2f(u16 u) {
  return __uint_as_float(((u32)u) << 16);
}
__device__ __forceinline__ void gl16(const void* g, void* l) {
  __builtin_amdgcn_global_load_lds((const __attribute__((address_space(1))) void*)g,
                                   (__attribute__((address_space(3))) void*)l, 16, 0, 0);
}
__device__ __forceinline__ u32 cvtpk(float a, float b) {
  u32 r;
  asm("v_cvt_pk_bf16_f32 %0, %1, %2" : "=v"(r) : "v"(a), "v"(b));
  return r;
}

// ---------------- fp32 -> bf16 convert, all 5 tensors in one launch ----------------
__global__ __launch_bounds__(256) void convert_all(
    const float* __restrict__ s0, u16* __restrict__ d0, int n0,
    const float* __restrict__ s1, u16* __restrict__ d1, int n1,
    const float* __restrict__ s2, u16* __restrict__ d2, int n2,
    const float* __restrict__ s3, u16* __restrict__ d3, int n3,
    const float* __restrict__ s4, u16* __restrict__ d4, int n4c) {
  const int stride = gridDim.x * blockDim.x;
  const int total = n0 + n1 + n2 + n3 + n4c;
  for (int i = blockIdx.x * blockDim.x + threadIdx.x; i < total; i += stride) {
    const float* s; u16* d; int j = i;
    if (j < n0) { s = s0; d = d0; }
    else { j -= n0;
      if (j < n1) { s = s1; d = d1; }
      else { j -= n1;
        if (j < n2) { s = s2; d = d2; }
        else { j -= n2;
          if (j < n3) { s = s3; d = d3; }
          else { j -= n3; s = s4; d = d4; }
        }
      }
    }
    float4 v = reinterpret_cast<const float4*>(s)[j];
    uint2 o;
    o.x = f2bf(v.x) | (f2bf(v.y) << 16);
    o.y = f2bf(v.z) | (f2bf(v.w) << 16);
    reinterpret_cast<uint2*>(d)[j] = o;
  }
}

// ---------------- YaRN cos/sin table (packed float2) ----------------
__global__ __launch_bounds__(256) void yarn_table(float2* __restrict__ cs) {
  int idx = blockIdx.x * blockDim.x + threadIdx.x;
  if (idx >= S_LEN * 32) return;
  int pos = idx >> 5, i = idx & 31;
  double pf = pow(500000.0, (double)i / 32.0);
  double sm = ((double)i - 9.0) / 9.0;             // low=9, high=18
  sm = sm < 0.0 ? 0.0 : (sm > 1.0 ? 1.0 : sm);
  double invf = (1.0 - sm) / (16.0 * pf) + sm / pf;
  float f = (float)pos * (float)invf;
  const float mscale = 1.2772588722239781f;        // 0.1*ln(16)+1
  cs[idx] = make_float2(cosf(f) * mscale, sinf(f) * mscale);
}

// ---------------- RMS norm (per-token over 512) ----------------
__global__ __launch_bounds__(256) void rmsnorm_kernel(const float* __restrict__ X,
                                                      const float* __restrict__ w,
                                                      u16* __restrict__ out) {
  int wid = threadIdx.x >> 6, lane = threadIdx.x & 63;
  int row = blockIdx.x * 4 + wid;
  const float* xr = X + (size_t)row * KVR;
  float4 v0 = reinterpret_cast<const float4*>(xr)[lane * 2];
  float4 v1 = reinterpret_cast<const float4*>(xr)[lane * 2 + 1];
  float ss = v0.x * v0.x + v0.y * v0.y + v0.z * v0.z + v0.w * v0.w +
             v1.x * v1.x + v1.y * v1.y + v1.z * v1.z + v1.w * v1.w;
  #pragma unroll
  for (int m = 1; m < 64; m <<= 1) ss += __shfl_xor(ss, m);
  float sc = rsqrtf(ss * (1.0f / KVR) + 1e-6f);
  const float* wr = w + lane * 8;
  uint4 o;
  o.x = f2bf(v0.x * sc * wr[0]) | (f2bf(v0.y * sc * wr[1]) << 16);
  o.y = f2bf(v0.z * sc * wr[2]) | (f2bf(v0.w * sc * wr[3]) << 16);
  o.z = f2bf(v1.x * sc * wr[4]) | (f2bf(v1.y * sc * wr[5]) << 16);
  o.w = f2bf(v1.z * sc * wr[6]) | (f2bf(v1.w * sc * wr[7]) << 16);
  reinterpret_cast<uint4*>(out)[(size_t)row * 64 + lane] = o;
}

// ---------------- GEMM: C(MxN) = A(MxK,bf16) @ W(NxK,bf16)^T ----------------
// 2-phase pipelined (dbuf + counted vmcnt(4)). XCD-chunked block swizzle.
// MODE 0: bf16 out. 1: f32 out. 2: fused q(+rope, +QSCALE)/kv_a split at 2048.
// 3: kv_b — K-part bf16 row-major (+rope d<64), V-part direct to Vt[bh][d][s].
template<int MODE>
__global__ __launch_bounds__(256) void gemm_bt(const u16* __restrict__ A,
                                               const u16* __restrict__ W,
                                               void* __restrict__ C0v,
                                               void* __restrict__ C1v,
                                               const float2* __restrict__ cs,
                                               int M, int N, int K) {
  __shared__ u16 As[2][128 * 32];
  __shared__ u16 Bs[2][128 * 32];
  const int tid = threadIdx.x;
  const int wid = tid >> 6;
  const int lane = tid & 63;
  const int r16 = lane & 15;
  const int kg = lane >> 4;
  // XCD-chunked swizzle (T1): nwg%8==0 for all launches -> bijective
  const int nwg = gridDim.x * gridDim.y;
  const int bid = blockIdx.y * gridDim.x + blockIdx.x;
  const int swz = (bid & 7) * (nwg >> 3) + (bid >> 3);
  const int bm = (swz / gridDim.x) * 128;
  const int bn = (swz % gridDim.x) * 128;
  const int wm = (wid >> 1) * 64;
  const int wn = (wid & 1) * 64;
  f32x4 acc[4][4] = {};
  const int srow = tid >> 2;
  const int sslot = tid & 3;
  const int ra = srow, rb = 64 + srow;
  const int ca = sslot ^ ((ra >> 1) & 3);
  const int cb = sslot ^ ((rb >> 1) & 3);
  const u16* a0 = A + (size_t)(bm + ra) * K + ca * 8;
  const u16* a1 = A + (size_t)(bm + rb) * K + cb * 8;
  const u16* b0 = W + (size_t)(bn + ra) * K + ca * 8;
  const u16* b1 = W + (size_t)(bn + rb) * K + cb * 8;

  auto stage = [&](int buf, int kt) {
    gl16(a0 + kt, &As[buf][wid * 512]);
    gl16(a1 + kt, &As[buf][wid * 512 + 2048]);
    gl16(b0 + kt, &Bs[buf][wid * 512]);
    gl16(b1 + kt, &Bs[buf][wid * 512 + 2048]);
  };

  const int NK = K / 32;
  stage(0, 0);
  for (int t = 0; t < NK; ++t) {
    const int cur = t & 1;
    if (t + 1 < NK) {
      stage(cur ^ 1, (t + 1) * 32);
      asm volatile("s_waitcnt vmcnt(4)" ::: "memory");
    } else {
      asm volatile("s_waitcnt vmcnt(0)" ::: "memory");
    }
    __builtin_amdgcn_s_barrier();
    short8 af[4], bfv[4];
    #pragma unroll
    for (int mi = 0; mi < 4; ++mi) {
      int row = wm + mi * 16 + r16;
      af[mi] = *reinterpret_cast<const short8*>(
          &As[cur][row * 32 + ((kg ^ ((row >> 1) & 3)) << 3)]);
    }
    #pragma unroll
    for (int ni = 0; ni < 4; ++ni) {
      int row = wn + ni * 16 + r16;
      bfv[ni] = *reinterpret_cast<const short8*>(
          &Bs[cur][row * 32 + ((kg ^ ((row >> 1) & 3)) << 3)]);
    }
    #pragma unroll
    for (int mi = 0; mi < 4; ++mi)
      #pragma unroll
      for (int ni = 0; ni < 4; ++ni)
        acc[mi][ni] = __builtin_amdgcn_mfma_f32_16x16x32_bf16(af[mi], bfv[ni], acc[mi][ni], 0, 0, 0);
    __builtin_amdgcn_s_barrier();
  }

  // fused RoPE on accumulators: pair (d, d+32) == fragments (ni, ni+2), wn==0 waves
  if (MODE == 2 || MODE == 3) {
    const bool doRope = (wn == 0) && (MODE == 2 ? (bn < 2048) : ((bn & 128) == 0));
    if (doRope) {
      #pragma unroll
      for (int mi = 0; mi < 4; ++mi) {
        const int t0 = bm + wm + mi * 16 + kg * 4;
        #pragma unroll
        for (int r = 0; r < 4; ++r) {
          const int pos = (t0 + r) & (S_LEN - 1);
          #pragma unroll
          for (int np = 0; np < 2; ++np) {
            float2 c = cs[pos * 32 + np * 16 + r16];
            float x1 = acc[mi][np][r], x2 = acc[mi][np + 2][r];
            acc[mi][np][r] = x1 * c.x - x2 * c.y;
            acc[mi][np + 2][r] = x2 * c.x + x1 * c.y;
          }
        }
      }
    }
  }

  if (MODE == 1) {
    float* C = (float*)C0v;
    #pragma unroll
    for (int mi = 0; mi < 4; ++mi)
      #pragma unroll
      for (int ni = 0; ni < 4; ++ni) {
        size_t base = (size_t)(bm + wm + mi * 16 + kg * 4) * N + (bn + wn + ni * 16 + r16);
        #pragma unroll
        for (int r = 0; r < 4; ++r) C[base + (size_t)r * N] = acc[mi][ni][r];
      }
  } else if (MODE == 2) {
    if (bn < 2048) {
      u16* C = (u16*)C0v;  // q_bf, row stride HID, pre-scaled by QSCALE
      #pragma unroll
      for (int mi = 0; mi < 4; ++mi)
        #pragma unroll
        for (int ni = 0; ni < 4; ++ni) {
          size_t base = (size_t)(bm + wm + mi * 16 + kg * 4) * HID + (bn + wn + ni * 16 + r16);
          #pragma unroll
          for (int r = 0; r < 4; ++r) C[base + (size_t)r * HID] = (u16)f2bf(acc[mi][ni][r] * QSCALE);
        }
    } else {
      float* C = (float*)C1v;  // lat_f, row stride KVR
      #pragma unroll
      for (int mi = 0; mi < 4; ++mi)
        #pragma unroll
        for (int ni = 0; ni < 4; ++ni) {
          size_t base = (size_t)(bm + wm + mi * 16 + kg * 4) * KVR +
                        (bn - 2048 + wn + ni * 16 + r16);
          #pragma unroll
          for (int r = 0; r < 4; ++r) C[base + (size_t)r * KVR] = acc[mi][ni][r];
        }
    }
  } else if (MODE == 3) {
    if ((bn & 128) == 0) {
      // K-part: bf16 row-major into kv (rope already applied above for d<64)
      u16* C = (u16*)C0v;
      #pragma unroll
      for (int mi = 0; mi < 4; ++mi)
        #pragma unroll
        for (int ni = 0; ni < 4; ++ni) {
          size_t base = (size_t)(bm + wm + mi * 16 + kg * 4) * N + (bn + wn + ni * 16 + r16);
          #pragma unroll
          for (int r = 0; r < 4; ++r) C[base + (size_t)r * N] = (u16)f2bf(acc[mi][ni][r]);
        }
    } else {
      // V-part: write transposed into Vt[bh][d][s]; 4 consecutive tokens -> uint2
      u16* Vt = (u16*)C1v;
      const int hh = bn >> 8;
      #pragma unroll
      for (int mi = 0; mi < 4; ++mi) {
        const int tok0 = bm + wm + mi * 16 + kg * 4;
        const int bb = tok0 >> 11, s = tok0 & (S_LEN - 1);
        #pragma unroll
        for (int ni = 0; ni < 4; ++ni) {
          const int d = wn + ni * 16 + r16;
          uint2 pk;
          pk.x = cvtpk(acc[mi][ni][0], acc[mi][ni][1]);
          pk.y = cvtpk(acc[mi][ni][2], acc[mi][ni][3]);
          *reinterpret_cast<uint2*>(
              &Vt[((size_t)((bb * 16 + hh) * 128 + d)) * S_LEN + s]) = pk;
        }
      }
    }
  } else {
    u16* C = (u16*)C0v;
    #pragma unroll
    for (int mi = 0; mi < 4; ++mi)
      #pragma unroll
      for (int ni = 0; ni < 4; ++ni) {
        size_t base = (size_t)(bm + wm + mi * 16 + kg * 4) * N + (bn + wn + ni * 16 + r16);
        #pragma unroll
        for (int r = 0; r < 4; ++r) C[base + (size_t)r * N] = (u16)f2bf(acc[mi][ni][r]);
      }
  }
}

// ---------------- flash attention v9b: KV-split x2, 40KB LDS, SAFE SYNC ----------
// r13 failure root-cause: single-buffered K/V + raw s_barrier — the raw barrier
// is not a compiler memory fence, so LDS reads could slip past it into the next
// iteration's overwrite (dbuf rounds were immune; single-buffer is not).
// Fix: __syncthreads() at both sync points (emits s_waitcnt vmcnt(0) lgkmcnt(0)
// + s_barrier, full compiler fence). No counted vmcnt anywhere -> spill-proof.
#define KVB 64
__global__ __launch_bounds__(256) __attribute__((amdgpu_num_vgpr(128)))
void attn_kernel(const u16* __restrict__ Q,
                 const u16* __restrict__ KV,
                 const u16* __restrict__ Vt,
                 u16* __restrict__ P0,      // = kv_bf (V-slot holes)
                 u16* __restrict__ P1,      // = attn_bf
                 float2* __restrict__ lse) {
  __shared__ u16 Ks[KVB * 128];   // [key][d], 16B slot ^ (key&7)
  __shared__ u16 Vs[128 * KVB];   // [d][key], 16B slot ^ (d&7)
  __shared__ u16 Ps[4][16 * 64];  // per-wave P[q][k], reused across q-blocks
  const int tid = threadIdx.x, wid = tid >> 6, lane = tid & 63;
  const int r16 = lane & 15, kg = lane >> 4;
  const int bh = blockIdx.x, b = bh >> 4, h = bh & 15;
  const int q0 = blockIdx.y * 128 + wid * 32;
  const int split = blockIdx.z;

  short8 qf0[4], qf1[4];
  {
    const size_t qr0 = ((size_t)(b * S_LEN) + q0 + r16) * HID + h * HD;
    #pragma unroll
    for (int ds = 0; ds < 4; ++ds) {
      qf0[ds] = *reinterpret_cast<const short8*>(&Q[qr0 + ds * 32 + kg * 8]);
      qf1[ds] = *reinterpret_cast<const short8*>(&Q[qr0 + (size_t)16 * HID + ds * 32 + kg * 8]);
    }
  }

  f32x4 oacc0[8] = {}, oacc1[8] = {};
  float m0 = -3.0e38f, l0 = 0.0f, m1 = -3.0e38f, l1 = 0.0f;

  const int krow = wid * 4 + (lane >> 4);            // + c*16
  const int kslot = (lane & 15) ^ (krow & 7);
  const u16* gK = KV + (size_t)(b * S_LEN) * 4096 + h * 256 + (size_t)krow * 4096 + kslot * 8;
  const int vrow = wid * 8 + (lane >> 3);            // + c*32
  const int vslot = (lane & 7) ^ (vrow & 7);
  const u16* gV = Vt + ((size_t)bh * 128 + vrow) * S_LEN + vslot * 8;

  auto stage = [&](int k0) {
    #pragma unroll
    for (int c = 0; c < 4; ++c) {
      gl16(gK + (size_t)(k0 + c * 16) * 4096, &Ks[(c * 256 + wid * 64) * 8]);
      gl16(gV + (size_t)c * 32 * S_LEN + k0, &Vs[(c * 256 + wid * 64) * 8]);
    }
  };

  auto qk = [&](short8 (&qf)[4], f32x4 (&sc)[4]) {
    #pragma unroll
    for (int nt = 0; nt < 4; ++nt) {
      sc[nt] = (f32x4){0.f, 0.f, 0.f, 0.f};
      const int key = nt * 16 + r16;
      #pragma unroll
      for (int ds = 0; ds < 4; ++ds) {
        short8 kf = *reinterpret_cast<const short8*>(
            &Ks[key * 128 + (((ds * 4 + kg) ^ (r16 & 7)) << 3)]);
        sc[nt] = __builtin_amdgcn_mfma_f32_16x16x32_bf16(kf, qf[ds], sc[nt], 0, 0, 0);
      }
    }
  };

  // scores arrive pre-scaled (QSCALE folded into Q): exp2 args are raw diffs
  auto softmax_store = [&](f32x4 (&sc)[4], float& mreg, float& lreg, f32x4 (&oa)[8]) {
    float mx = fmaxf(fmaxf(fmaxf(sc[0][0], sc[0][1]), fmaxf(sc[0][2], sc[0][3])),
                     fmaxf(fmaxf(sc[1][0], sc[1][1]), fmaxf(sc[1][2], sc[1][3])));
    mx = fmaxf(mx, fmaxf(fmaxf(fmaxf(sc[2][0], sc[2][1]), fmaxf(sc[2][2], sc[2][3])),
                         fmaxf(fmaxf(sc[3][0], sc[3][1]), fmaxf(sc[3][2], sc[3][3]))));
    mx = fmaxf(mx, __shfl_xor(mx, 16));
    mx = fmaxf(mx, __shfl_xor(mx, 32));
    if (!__all(mx - mreg <= 8.0f)) {             // defer-max: P bounded by 2^8
      float nm = fmaxf(mreg, mx);
      float al = __builtin_amdgcn_exp2f(mreg - nm);
      mreg = nm;
      lreg *= al;
      float ar0 = __shfl(al, kg * 4 + 0), ar1 = __shfl(al, kg * 4 + 1);
      float ar2 = __shfl(al, kg * 4 + 2), ar3 = __shfl(al, kg * 4 + 3);
      #pragma unroll
      for (int db = 0; db < 8; ++db) {
        oa[db][0] *= ar0; oa[db][1] *= ar1; oa[db][2] *= ar2; oa[db][3] *= ar3;
      }
    }
    const float nm = mreg;
    float s0 = 0.f;
    #pragma unroll
    for (int nt = 0; nt < 4; ++nt) {
      float p0 = __builtin_amdgcn_exp2f(sc[nt][0] - nm);
      float p1 = __builtin_amdgcn_exp2f(sc[nt][1] - nm);
      float p2 = __builtin_amdgcn_exp2f(sc[nt][2] - nm);
      float p3 = __builtin_amdgcn_exp2f(sc[nt][3] - nm);
      s0 += (p0 + p1) + (p2 + p3);
      uint2 pk;
      pk.x = cvtpk(p0, p1);
      pk.y = cvtpk(p2, p3);
      *reinterpret_cast<uint2*>(
          &Ps[wid][(r16 * 64 + nt * 16 + kg * 4) ^ ((r16 & 7) << 3)]) = pk;
    }
    s0 += __shfl_xor(s0, 16);
    s0 += __shfl_xor(s0, 32);
    lreg += s0;
  };

  auto pv = [&](f32x4 (&oa)[8]) {
    #pragma unroll
    for (int ks = 0; ks < 2; ++ks) {
      const int pidx = (r16 * 64 + ks * 32 + kg * 8) ^ ((r16 & 7) << 3);
      short8 pa = *reinterpret_cast<const short8*>(&Ps[wid][pidx]);
      #pragma unroll
      for (int db = 0; db < 8; ++db) {
        const int drow = db * 16 + r16;
        short8 vf = *reinterpret_cast<const short8*>(
            &Vs[drow * 64 + (((ks * 4 + kg) ^ (r16 & 7)) << 3)]);
        oa[db] = __builtin_amdgcn_mfma_f32_16x16x32_bf16(pa, vf, oa[db], 0, 0, 0);
      }
    }
  };

  const int kbase = split * (S_LEN / 2);
  for (int it = 0; it < (S_LEN / 2) / KVB; ++it) {
    stage(kbase + it * KVB);
    __syncthreads();                     // drain vmcnt(0)+lgkmcnt(0) + barrier (safe)

    f32x4 sc[4];
    qk(qf0, sc);
    softmax_store(sc, m0, l0, oacc0);
    pv(oacc0);
    __builtin_amdgcn_sched_barrier(0);   // sm1's P-writes must not pass PV0's P-reads
    qk(qf1, sc);
    softmax_store(sc, m1, l1, oacc1);
    pv(oacc1);
    __syncthreads();                     // all LDS reads drained before next overwrite
  }

  // epilogue: unnormalized partial O (bf16) + (m,l) per row
  {
    u16* Op;
    size_t stride;
    if (split == 0) { Op = P0 + h * 256 + 128; stride = 4096; }
    else            { Op = P1 + h * 128;       stride = 2048; }
    #pragma unroll
    for (int db = 0; db < 8; ++db)
      #pragma unroll
      for (int r = 0; r < 4; ++r) {
        size_t row = (size_t)(b * S_LEN) + q0 + kg * 4 + r;
        Op[row * stride + db * 16 + r16] = (u16)f2bf(oacc0[db][r]);
        Op[(row + 16) * stride + db * 16 + r16] = (u16)f2bf(oacc1[db][r]);
      }
    if (kg == 0) {
      float2* L = lse + (size_t)split * (32 * S_LEN) + (size_t)bh * S_LEN;
      L[q0 + r16] = make_float2(m0, l0);
      L[q0 + 16 + r16] = make_float2(m1, l1);
    }
  }
}

// ---------------- combine: out = (P0*e0 + P1*e1) / (l0*e0 + l1*e1) ----------------
__global__ __launch_bounds__(256) void combine_kernel(const u16* __restrict__ P0,
                                                      u16* __restrict__ P1,
                                                      const float2* __restrict__ lse) {
  const int row = blockIdx.x * 16 + (threadIdx.x >> 4);   // (tok, h)
  const int tok = row >> 4, h = row & 15;
  const int b = tok >> 11, q = tok & (S_LEN - 1);
  const int bh = b * 16 + h;
  float2 a0 = lse[(size_t)bh * S_LEN + q];
  float2 a1 = lse[(size_t)32 * S_LEN + (size_t)bh * S_LEN + q];
  float M = fmaxf(a0.x, a1.x);
  float e0 = __builtin_amdgcn_exp2f(a0.x - M);
  float e1 = __builtin_amdgcn_exp2f(a1.x - M);
  float dn = 1.0f / (a0.y * e0 + a1.y * e1);
  float w0 = e0 * dn, w1 = e1 * dn;
  const int dg = (threadIdx.x & 15) * 8;
  const u16* p0 = P0 + (size_t)tok * 4096 + h * 256 + 128 + dg;
  u16* p1 = P1 + (size_t)tok * 2048 + h * 128 + dg;
  uint4 v0 = *reinterpret_cast<const uint4*>(p0);
  uint4 v1 = *reinterpret_cast<const uint4*>(p1);
  const u16* s0 = reinterpret_cast<const u16*>(&v0);
  const u16* s1 = reinterpret_cast<const u16*>(&v1);
  u16 o[8] __attribute__((aligned(16)));
  #pragma unroll
  for (int j = 0; j < 8; ++j)
    o[j] = (u16)f2bf(bf2f(s0[j]) * w0 + bf2f(s1[j]) * w1);
  *reinterpret_cast<uint4*>(p1) = *reinterpret_cast<const uint4*>(o);
}

// ---------------- launch ----------------
extern "C" void kernel_launch(void* const* d_in, const int* in_sizes, int n_in,
                              void* d_out, int out_size, void* d_ws, size_t ws_size,
                              hipStream_t stream) {
  (void)in_sizes; (void)n_in; (void)out_size; (void)ws_size;
  const float* hidden = (const float*)d_in[0];
  const float* q_w    = (const float*)d_in[1];
  const float* kv_a_w = (const float*)d_in[2];
  const float* kv_b_w = (const float*)d_in[3];
  const float* o_w    = (const float*)d_in[4];
  const float* nw     = (const float*)d_in[5];

  char* ws = (char*)d_ws;
  size_t off = 0;
  auto carve = [&](size_t n) { void* p = ws + off; off += (n + 255) & ~(size_t)255; return p; };
  u16* h_bf    = (u16*)carve((size_t)TOKENS * HID * 2);
  u16* qaw_bf  = (u16*)carve((size_t)2560 * HID * 2);   // q_w (2048) ++ kv_a_w[64:] (512)
  u16* kvbw_bf = (u16*)carve((size_t)4096 * KVR * 2);
  u16* ow_bf   = (u16*)carve((size_t)HID * HID * 2);
  u16* q_bf    = (u16*)carve((size_t)TOKENS * HID * 2);
  float* lat_f = (float*)carve((size_t)TOKENS * KVR * 4);
  u16* lat_bf  = (u16*)carve((size_t)TOKENS * KVR * 2);
  u16* kv_bf   = (u16*)carve((size_t)TOKENS * 4096 * 2);
  float2* cs_t = (float2*)carve((size_t)S_LEN * 32 * 8);
  u16* attn_bf = (u16*)carve((size_t)TOKENS * HID * 2);
  u16* vt_bf   = h_bf;             // alias: h_bf dead after fused qa GEMM
  float2* lse  = (float2*)lat_f;   // alias: lat_f dead after rmsnorm (needs 1MB of 8MB)

  dim3 blk(256);

  convert_all<<<dim3(2048), blk, 0, stream>>>(
      hidden, h_bf, TOKENS * HID / 4,
      q_w, qaw_bf, HID * HID / 4,
      kv_a_w + 64 * HID, qaw_bf + (size_t)2048 * HID, KVR * HID / 4,
      kv_b_w, kvbw_bf, 4096 * KVR / 4,
      o_w, ow_bf, HID * HID / 4);
  yarn_table<<<dim3(S_LEN * 32 / 256), blk, 0, stream>>>(cs_t);

  // fused q-proj (+RoPE, +QSCALE) and kv_a: N = 2048 + 512 = 2560 (640 blocks)
  gemm_bt<2><<<dim3(2560 / 128, TOKENS / 128), blk, 0, stream>>>(
      h_bf, qaw_bf, q_bf, lat_f, cs_t, TOKENS, 2560, HID);
  rmsnorm_kernel<<<dim3(TOKENS / 4), blk, 0, stream>>>(lat_f, nw, lat_bf);
  // kv_b: K-part (+RoPE) row-major, V-part direct-transposed to Vt (1024 blocks)
  gemm_bt<3><<<dim3(4096 / 128, TOKENS / 128), blk, 0, stream>>>(
      lat_bf, kvbw_bf, kv_bf, vt_bf, cs_t, TOKENS, 4096, KVR);

  // KV-split flash attention: 32 bh x 16 q-chunks x 2 splits = 1024 blocks (4/CU)
  attn_kernel<<<dim3(BATCH * NH, S_LEN / 128, 2), blk, 0, stream>>>(
      q_bf, kv_bf, vt_bf, kv_bf, attn_bf, lse);
  combine_kernel<<<dim3(TOKENS * NH / 16), blk, 0, stream>>>(kv_bf, attn_bf, lse);

  // o-proj (512 blocks)
  gemm_bt<1><<<dim3(HID / 128, TOKENS / 128), blk, 0, stream>>>(
      attn_bf, ow_bf, (float*)d_out, nullptr, cs_t, TOKENS, HID, HID);
}

// Round 15
// 244.607 us; speedup vs baseline: 1.0973x; 1.0973x over previous
//
#include <hip/hip_runtime.h>

typedef unsigned short u16;
typedef unsigned int u32;
typedef __attribute__((ext_vector_type(4))) float f32x4;
typedef __attribute__((ext_vector_type(8))) short short8;

#define S_LEN 2048
#define BATCH 2
#define HID 2048
#define NH 16
#define HD 128
#define KVR 512
#define TOKENS 4096
// log2(e)/sqrt(HD): folded into Q at GEMM epilogue so attn exp2 takes raw sc
#define QSCALE 0.12751879523243842f

__device__ __forceinline__ u32 f2bf(float f) {
  u32 b = __float_as_uint(f);
  return (b + 0x7FFFu + ((b >> 16) & 1u)) >> 16;
}
__device__ __forceinline__ float bf2f(u16 u) {
  return __uint_as_float(((u32)u) << 16);
}
__device__ __forceinline__ void gl16(const void* g, void* l) {
  __builtin_amdgcn_global_load_lds((const __attribute__((address_space(1))) void*)g,
                                   (__attribute__((address_space(3))) void*)l, 16, 0, 0);
}
__device__ __forceinline__ u32 cvtpk(float a, float b) {
  u32 r;
  asm("v_cvt_pk_bf16_f32 %0, %1, %2" : "=v"(r) : "v"(a), "v"(b));
  return r;
}

// ---------------- fp32 -> bf16 convert, all 5 tensors in one launch ----------------
__global__ __launch_bounds__(256) void convert_all(
    const float* __restrict__ s0, u16* __restrict__ d0, int n0,
    const float* __restrict__ s1, u16* __restrict__ d1, int n1,
    const float* __restrict__ s2, u16* __restrict__ d2, int n2,
    const float* __restrict__ s3, u16* __restrict__ d3, int n3,
    const float* __restrict__ s4, u16* __restrict__ d4, int n4c) {
  const int stride = gridDim.x * blockDim.x;
  const int total = n0 + n1 + n2 + n3 + n4c;
  for (int i = blockIdx.x * blockDim.x + threadIdx.x; i < total; i += stride) {
    const float* s; u16* d; int j = i;
    if (j < n0) { s = s0; d = d0; }
    else { j -= n0;
      if (j < n1) { s = s1; d = d1; }
      else { j -= n1;
        if (j < n2) { s = s2; d = d2; }
        else { j -= n2;
          if (j < n3) { s = s3; d = d3; }
          else { j -= n3; s = s4; d = d4; }
        }
      }
    }
    float4 v = reinterpret_cast<const float4*>(s)[j];
    uint2 o;
    o.x = f2bf(v.x) | (f2bf(v.y) << 16);
    o.y = f2bf(v.z) | (f2bf(v.w) << 16);
    reinterpret_cast<uint2*>(d)[j] = o;
  }
}

// ---------------- YaRN cos/sin table (packed float2) ----------------
__global__ __launch_bounds__(256) void yarn_table(float2* __restrict__ cs) {
  int idx = blockIdx.x * blockDim.x + threadIdx.x;
  if (idx >= S_LEN * 32) return;
  int pos = idx >> 5, i = idx & 31;
  double pf = pow(500000.0, (double)i / 32.0);
  double sm = ((double)i - 9.0) / 9.0;             // low=9, high=18
  sm = sm < 0.0 ? 0.0 : (sm > 1.0 ? 1.0 : sm);
  double invf = (1.0 - sm) / (16.0 * pf) + sm / pf;
  float f = (float)pos * (float)invf;
  const float mscale = 1.2772588722239781f;        // 0.1*ln(16)+1
  cs[idx] = make_float2(cosf(f) * mscale, sinf(f) * mscale);
}

// ---------------- RMS norm (per-token over 512) ----------------
__global__ __launch_bounds__(256) void rmsnorm_kernel(const float* __restrict__ X,
                                                      const float* __restrict__ w,
                                                      u16* __restrict__ out) {
  int wid = threadIdx.x >> 6, lane = threadIdx.x & 63;
  int row = blockIdx.x * 4 + wid;
  const float* xr = X + (size_t)row * KVR;
  float4 v0 = reinterpret_cast<const float4*>(xr)[lane * 2];
  float4 v1 = reinterpret_cast<const float4*>(xr)[lane * 2 + 1];
  float ss = v0.x * v0.x + v0.y * v0.y + v0.z * v0.z + v0.w * v0.w +
             v1.x * v1.x + v1.y * v1.y + v1.z * v1.z + v1.w * v1.w;
  #pragma unroll
  for (int m = 1; m < 64; m <<= 1) ss += __shfl_xor(ss, m);
  float sc = rsqrtf(ss * (1.0f / KVR) + 1e-6f);
  const float* wr = w + lane * 8;
  uint4 o;
  o.x = f2bf(v0.x * sc * wr[0]) | (f2bf(v0.y * sc * wr[1]) << 16);
  o.y = f2bf(v0.z * sc * wr[2]) | (f2bf(v0.w * sc * wr[3]) << 16);
  o.z = f2bf(v1.x * sc * wr[4]) | (f2bf(v1.y * sc * wr[5]) << 16);
  o.w = f2bf(v1.z * sc * wr[6]) | (f2bf(v1.w * sc * wr[7]) << 16);
  reinterpret_cast<uint4*>(out)[(size_t)row * 64 + lane] = o;
}

// ---------------- GEMM: C(MxN) = A(MxK,bf16) @ W(NxK,bf16)^T ----------------
// 2-phase pipelined (dbuf + counted vmcnt(4)). XCD-chunked block swizzle:
// consecutive swizzled blocks share an A-panel and land on one XCD's L2
// (bijective: all grids have nwg % 8 == 0).
// MODE 0: bf16 out. 1: f32 out. 2: fused q(+rope, +QSCALE)/kv_a split at 2048.
// 3: kv_b — K-part bf16 row-major (+rope d<64), V-part direct to Vt[bh][d][s].
template<int MODE>
__global__ __launch_bounds__(256) void gemm_bt(const u16* __restrict__ A,
                                               const u16* __restrict__ W,
                                               void* __restrict__ C0v,
                                               void* __restrict__ C1v,
                                               const float2* __restrict__ cs,
                                               int M, int N, int K) {
  __shared__ u16 As[2][128 * 32];
  __shared__ u16 Bs[2][128 * 32];
  const int tid = threadIdx.x;
  const int wid = tid >> 6;
  const int lane = tid & 63;
  const int r16 = lane & 15;
  const int kg = lane >> 4;
  // XCD-chunked swizzle (T1): nwg%8==0 for all launches -> bijective
  const int nwg = gridDim.x * gridDim.y;
  const int bid = blockIdx.y * gridDim.x + blockIdx.x;
  const int swz = (bid & 7) * (nwg >> 3) + (bid >> 3);
  const int bm = (swz / gridDim.x) * 128;
  const int bn = (swz % gridDim.x) * 128;
  const int wm = (wid >> 1) * 64;
  const int wn = (wid & 1) * 64;
  f32x4 acc[4][4] = {};
  const int srow = tid >> 2;
  const int sslot = tid & 3;
  const int ra = srow, rb = 64 + srow;
  const int ca = sslot ^ ((ra >> 1) & 3);
  const int cb = sslot ^ ((rb >> 1) & 3);
  const u16* a0 = A + (size_t)(bm + ra) * K + ca * 8;
  const u16* a1 = A + (size_t)(bm + rb) * K + cb * 8;
  const u16* b0 = W + (size_t)(bn + ra) * K + ca * 8;
  const u16* b1 = W + (size_t)(bn + rb) * K + cb * 8;

  auto stage = [&](int buf, int kt) {
    gl16(a0 + kt, &As[buf][wid * 512]);
    gl16(a1 + kt, &As[buf][wid * 512 + 2048]);
    gl16(b0 + kt, &Bs[buf][wid * 512]);
    gl16(b1 + kt, &Bs[buf][wid * 512 + 2048]);
  };

  const int NK = K / 32;
  stage(0, 0);
  for (int t = 0; t < NK; ++t) {
    const int cur = t & 1;
    if (t + 1 < NK) {
      stage(cur ^ 1, (t + 1) * 32);
      asm volatile("s_waitcnt vmcnt(4)" ::: "memory");
    } else {
      asm volatile("s_waitcnt vmcnt(0)" ::: "memory");
    }
    __builtin_amdgcn_s_barrier();
    short8 af[4], bfv[4];
    #pragma unroll
    for (int mi = 0; mi < 4; ++mi) {
      int row = wm + mi * 16 + r16;
      af[mi] = *reinterpret_cast<const short8*>(
          &As[cur][row * 32 + ((kg ^ ((row >> 1) & 3)) << 3)]);
    }
    #pragma unroll
    for (int ni = 0; ni < 4; ++ni) {
      int row = wn + ni * 16 + r16;
      bfv[ni] = *reinterpret_cast<const short8*>(
          &Bs[cur][row * 32 + ((kg ^ ((row >> 1) & 3)) << 3)]);
    }
    #pragma unroll
    for (int mi = 0; mi < 4; ++mi)
      #pragma unroll
      for (int ni = 0; ni < 4; ++ni)
        acc[mi][ni] = __builtin_amdgcn_mfma_f32_16x16x32_bf16(af[mi], bfv[ni], acc[mi][ni], 0, 0, 0);
    __builtin_amdgcn_s_barrier();
  }

  // fused RoPE on accumulators: pair (d, d+32) == fragments (ni, ni+2), wn==0 waves
  if (MODE == 2 || MODE == 3) {
    const bool doRope = (wn == 0) && (MODE == 2 ? (bn < 2048) : ((bn & 128) == 0));
    if (doRope) {
      #pragma unroll
      for (int mi = 0; mi < 4; ++mi) {
        const int t0 = bm + wm + mi * 16 + kg * 4;
        #pragma unroll
        for (int r = 0; r < 4; ++r) {
          const int pos = (t0 + r) & (S_LEN - 1);
          #pragma unroll
          for (int np = 0; np < 2; ++np) {
            float2 c = cs[pos * 32 + np * 16 + r16];
            float x1 = acc[mi][np][r], x2 = acc[mi][np + 2][r];
            acc[mi][np][r] = x1 * c.x - x2 * c.y;
            acc[mi][np + 2][r] = x2 * c.x + x1 * c.y;
          }
        }
      }
    }
  }

  if (MODE == 1) {
    float* C = (float*)C0v;
    #pragma unroll
    for (int mi = 0; mi < 4; ++mi)
      #pragma unroll
      for (int ni = 0; ni < 4; ++ni) {
        size_t base = (size_t)(bm + wm + mi * 16 + kg * 4) * N + (bn + wn + ni * 16 + r16);
        #pragma unroll
        for (int r = 0; r < 4; ++r) C[base + (size_t)r * N] = acc[mi][ni][r];
      }
  } else if (MODE == 2) {
    if (bn < 2048) {
      u16* C = (u16*)C0v;  // q_bf, row stride HID, pre-scaled by QSCALE
      #pragma unroll
      for (int mi = 0; mi < 4; ++mi)
        #pragma unroll
        for (int ni = 0; ni < 4; ++ni) {
          size_t base = (size_t)(bm + wm + mi * 16 + kg * 4) * HID + (bn + wn + ni * 16 + r16);
          #pragma unroll
          for (int r = 0; r < 4; ++r) C[base + (size_t)r * HID] = (u16)f2bf(acc[mi][ni][r] * QSCALE);
        }
    } else {
      float* C = (float*)C1v;  // lat_f, row stride KVR
      #pragma unroll
      for (int mi = 0; mi < 4; ++mi)
        #pragma unroll
        for (int ni = 0; ni < 4; ++ni) {
          size_t base = (size_t)(bm + wm + mi * 16 + kg * 4) * KVR +
                        (bn - 2048 + wn + ni * 16 + r16);
          #pragma unroll
          for (int r = 0; r < 4; ++r) C[base + (size_t)r * KVR] = acc[mi][ni][r];
        }
    }
  } else if (MODE == 3) {
    if ((bn & 128) == 0) {
      // K-part: bf16 row-major into kv (rope already applied above for d<64)
      u16* C = (u16*)C0v;
      #pragma unroll
      for (int mi = 0; mi < 4; ++mi)
        #pragma unroll
        for (int ni = 0; ni < 4; ++ni) {
          size_t base = (size_t)(bm + wm + mi * 16 + kg * 4) * N + (bn + wn + ni * 16 + r16);
          #pragma unroll
          for (int r = 0; r < 4; ++r) C[base + (size_t)r * N] = (u16)f2bf(acc[mi][ni][r]);
        }
    } else {
      // V-part: write transposed into Vt[bh][d][s]; 4 consecutive tokens -> uint2
      u16* Vt = (u16*)C1v;
      const int hh = bn >> 8;
      #pragma unroll
      for (int mi = 0; mi < 4; ++mi) {
        const int tok0 = bm + wm + mi * 16 + kg * 4;
        const int bb = tok0 >> 11, s = tok0 & (S_LEN - 1);
        #pragma unroll
        for (int ni = 0; ni < 4; ++ni) {
          const int d = wn + ni * 16 + r16;
          uint2 pk;
          pk.x = cvtpk(acc[mi][ni][0], acc[mi][ni][1]);
          pk.y = cvtpk(acc[mi][ni][2], acc[mi][ni][3]);
          *reinterpret_cast<uint2*>(
              &Vt[((size_t)((bb * 16 + hh) * 128 + d)) * S_LEN + s]) = pk;
        }
      }
    }
  } else {
    u16* C = (u16*)C0v;
    #pragma unroll
    for (int mi = 0; mi < 4; ++mi)
      #pragma unroll
      for (int ni = 0; ni < 4; ++ni) {
        size_t base = (size_t)(bm + wm + mi * 16 + kg * 4) * N + (bn + wn + ni * 16 + r16);
        #pragma unroll
        for (int r = 0; r < 4; ++r) C[base + (size_t)r * N] = (u16)f2bf(acc[mi][ni][r]);
      }
  }
}

// ---------------- flash attention (r10-exact: split QK^T, KVB=64, VGPR capped) -------
// Measured-best attn: 105.5 us, VGPR 88, spill-free under the 128 cap.
// r11: occupancy is grid-limited (512 blocks = 2/CU); LDS shrink doesn't help.
// r13/r14: KV-split x2 raises neither occupancy nor perf (2x HBM + combine).
#define KVB 64
__global__ __launch_bounds__(256) __attribute__((amdgpu_num_vgpr(128)))
void attn_kernel(const u16* __restrict__ Q,
                 const u16* __restrict__ KV,
                 const u16* __restrict__ Vt,
                 u16* __restrict__ O) {
  __shared__ u16 Ks[2][KVB * 128];   // [key][d], 16B slot ^ (key&7)
  __shared__ u16 Vs[2][128 * KVB];   // [d][key], 16B slot ^ (d&7)
  __shared__ u16 Ps[4][2][16 * 64];  // per-wave P[q][k]
  const int tid = threadIdx.x, wid = tid >> 6, lane = tid & 63;
  const int r16 = lane & 15, kg = lane >> 4;
  const int bh = blockIdx.x, b = bh >> 4, h = bh & 15;
  const int q0 = blockIdx.y * 128 + wid * 32;

  short8 qf0[4], qf1[4];
  {
    const size_t qr0 = ((size_t)(b * S_LEN) + q0 + r16) * HID + h * HD;
    #pragma unroll
    for (int ds = 0; ds < 4; ++ds) {
      qf0[ds] = *reinterpret_cast<const short8*>(&Q[qr0 + ds * 32 + kg * 8]);
      qf1[ds] = *reinterpret_cast<const short8*>(&Q[qr0 + (size_t)16 * HID + ds * 32 + kg * 8]);
    }
  }
  asm volatile("s_waitcnt vmcnt(0)" ::: "memory");

  f32x4 oacc0[8] = {}, oacc1[8] = {};
  float m0 = -3.0e38f, l0 = 0.0f, m1 = -3.0e38f, l1 = 0.0f;

  const int krow = wid * 4 + (lane >> 4);            // + c*16
  const int kslot = (lane & 15) ^ (krow & 7);
  const u16* gK = KV + (size_t)(b * S_LEN) * 4096 + h * 256 + (size_t)krow * 4096 + kslot * 8;
  const int vrow = wid * 8 + (lane >> 3);            // + c*32
  const int vslot = (lane & 7) ^ (vrow & 7);
  const u16* gV = Vt + ((size_t)bh * 128 + vrow) * S_LEN + vslot * 8;

  auto stage = [&](int buf, int it) {
    const int k0 = it * KVB;
    #pragma unroll
    for (int c = 0; c < 4; ++c) {
      gl16(gK + (size_t)(k0 + c * 16) * 4096, &Ks[buf][(c * 256 + wid * 64) * 8]);
      gl16(gV + (size_t)c * 32 * S_LEN + k0, &Vs[buf][(c * 256 + wid * 64) * 8]);
    }
  };

  auto qk = [&](const u16* Kc, short8 (&qf)[4], f32x4 (&sc)[4]) {
    #pragma unroll
    for (int nt = 0; nt < 4; ++nt) {
      sc[nt] = (f32x4){0.f, 0.f, 0.f, 0.f};
      const int key = nt * 16 + r16;
      #pragma unroll
      for (int ds = 0; ds < 4; ++ds) {
        short8 kf = *reinterpret_cast<const short8*>(
            &Kc[key * 128 + (((ds * 4 + kg) ^ (r16 & 7)) << 3)]);
        sc[nt] = __builtin_amdgcn_mfma_f32_16x16x32_bf16(kf, qf[ds], sc[nt], 0, 0, 0);
      }
    }
  };

  // scores arrive pre-scaled (QSCALE folded into Q): exp2 args are raw diffs
  auto softmax_store = [&](f32x4 (&sc)[4], float& mreg, float& lreg, f32x4 (&oa)[8],
                           u16* psbase) {
    float mx = fmaxf(fmaxf(fmaxf(sc[0][0], sc[0][1]), fmaxf(sc[0][2], sc[0][3])),
                     fmaxf(fmaxf(sc[1][0], sc[1][1]), fmaxf(sc[1][2], sc[1][3])));
    mx = fmaxf(mx, fmaxf(fmaxf(fmaxf(sc[2][0], sc[2][1]), fmaxf(sc[2][2], sc[2][3])),
                         fmaxf(fmaxf(sc[3][0], sc[3][1]), fmaxf(sc[3][2], sc[3][3]))));
    mx = fmaxf(mx, __shfl_xor(mx, 16));
    mx = fmaxf(mx, __shfl_xor(mx, 32));
    if (!__all(mx - mreg <= 8.0f)) {             // defer-max: P bounded by 2^8
      float nm = fmaxf(mreg, mx);
      float al = __builtin_amdgcn_exp2f(mreg - nm);
      mreg = nm;
      lreg *= al;
      float ar0 = __shfl(al, kg * 4 + 0), ar1 = __shfl(al, kg * 4 + 1);
      float ar2 = __shfl(al, kg * 4 + 2), ar3 = __shfl(al, kg * 4 + 3);
      #pragma unroll
      for (int db = 0; db < 8; ++db) {
        oa[db][0] *= ar0; oa[db][1] *= ar1; oa[db][2] *= ar2; oa[db][3] *= ar3;
      }
    }
    const float nm = mreg;
    float s0 = 0.f;
    #pragma unroll
    for (int nt = 0; nt < 4; ++nt) {
      float p0 = __builtin_amdgcn_exp2f(sc[nt][0] - nm);
      float p1 = __builtin_amdgcn_exp2f(sc[nt][1] - nm);
      float p2 = __builtin_amdgcn_exp2f(sc[nt][2] - nm);
      float p3 = __builtin_amdgcn_exp2f(sc[nt][3] - nm);
      s0 += (p0 + p1) + (p2 + p3);
      uint2 pk;
      pk.x = cvtpk(p0, p1);
      pk.y = cvtpk(p2, p3);
      *reinterpret_cast<uint2*>(
          &psbase[(r16 * 64 + nt * 16 + kg * 4) ^ ((r16 & 7) << 3)]) = pk;
    }
    s0 += __shfl_xor(s0, 16);
    s0 += __shfl_xor(s0, 32);
    lreg += s0;
  };

  stage(0, 0);
  for (int it = 0; it < S_LEN / KVB; ++it) {
    const int cur = it & 1;
    if (it + 1 < S_LEN / KVB) {
      stage(cur ^ 1, it + 1);
      asm volatile("s_waitcnt vmcnt(8)" ::: "memory");
    } else {
      asm volatile("s_waitcnt vmcnt(0)" ::: "memory");
    }
    __builtin_amdgcn_s_barrier();

    const u16* Kc = &Ks[cur][0];
    f32x4 sc[4];
    qk(Kc, qf0, sc);
    softmax_store(sc, m0, l0, oacc0, &Ps[wid][0][0]);
    __builtin_amdgcn_sched_barrier(0);   // pin: sc regs die before QK1 reuses them
    qk(Kc, qf1, sc);
    softmax_store(sc, m1, l1, oacc1, &Ps[wid][1][0]);
    __builtin_amdgcn_sched_barrier(0);

    const u16* Vc = &Vs[cur][0];
    #pragma unroll
    for (int ks = 0; ks < 2; ++ks) {
      const int pidx = (r16 * 64 + ks * 32 + kg * 8) ^ ((r16 & 7) << 3);
      short8 pa0 = *reinterpret_cast<const short8*>(&Ps[wid][0][pidx]);
      short8 pa1 = *reinterpret_cast<const short8*>(&Ps[wid][1][pidx]);
      #pragma unroll
      for (int db = 0; db < 8; ++db) {
        const int drow = db * 16 + r16;
        short8 vf = *reinterpret_cast<const short8*>(
            &Vc[drow * 64 + (((ks * 4 + kg) ^ (r16 & 7)) << 3)]);
        oacc0[db] = __builtin_amdgcn_mfma_f32_16x16x32_bf16(pa0, vf, oacc0[db], 0, 0, 0);
        oacc1[db] = __builtin_amdgcn_mfma_f32_16x16x32_bf16(pa1, vf, oacc1[db], 0, 0, 0);
      }
    }
    __builtin_amdgcn_s_barrier();
  }

  {
    float li0 = 1.0f / l0, li1 = 1.0f / l1;
    float lr0[4], lr1[4];
    #pragma unroll
    for (int r = 0; r < 4; ++r) {
      lr0[r] = __shfl(li0, kg * 4 + r);
      lr1[r] = __shfl(li1, kg * 4 + r);
    }
    #pragma unroll
    for (int db = 0; db < 8; ++db)
      #pragma unroll
      for (int r = 0; r < 4; ++r) {
        size_t i0 = ((size_t)(b * S_LEN) + q0 + kg * 4 + r) * HID + h * HD + db * 16 + r16;
        O[i0] = (u16)f2bf(oacc0[db][r] * lr0[r]);
        O[i0 + (size_t)16 * HID] = (u16)f2bf(oacc1[db][r] * lr1[r]);
      }
  }
}

// ---------------- launch ----------------
extern "C" void kernel_launch(void* const* d_in, const int* in_sizes, int n_in,
                              void* d_out, int out_size, void* d_ws, size_t ws_size,
                              hipStream_t stream) {
  (void)in_sizes; (void)n_in; (void)out_size; (void)ws_size;
  const float* hidden = (const float*)d_in[0];
  const float* q_w    = (const float*)d_in[1];
  const float* kv_a_w = (const float*)d_in[2];
  const float* kv_b_w = (const float*)d_in[3];
  const float* o_w    = (const float*)d_in[4];
  const float* nw     = (const float*)d_in[5];

  char* ws = (char*)d_ws;
  size_t off = 0;
  auto carve = [&](size_t n) { void* p = ws + off; off += (n + 255) & ~(size_t)255; return p; };
  u16* h_bf    = (u16*)carve((size_t)TOKENS * HID * 2);
  u16* qaw_bf  = (u16*)carve((size_t)2560 * HID * 2);   // q_w (2048) ++ kv_a_w[64:] (512)
  u16* kvbw_bf = (u16*)carve((size_t)4096 * KVR * 2);
  u16* ow_bf   = (u16*)carve((size_t)HID * HID * 2);
  u16* q_bf    = (u16*)carve((size_t)TOKENS * HID * 2);
  float* lat_f = (float*)carve((size_t)TOKENS * KVR * 4);
  u16* lat_bf  = (u16*)carve((size_t)TOKENS * KVR * 2);
  u16* kv_bf   = (u16*)carve((size_t)TOKENS * 4096 * 2);
  float2* cs_t = (float2*)carve((size_t)S_LEN * 32 * 8);
  u16* attn_bf = (u16*)carve((size_t)TOKENS * HID * 2);
  u16* vt_bf   = h_bf;  // alias: h_bf dead after fused qa GEMM; kv_b writes Vt here

  dim3 blk(256);

  convert_all<<<dim3(2048), blk, 0, stream>>>(
      hidden, h_bf, TOKENS * HID / 4,
      q_w, qaw_bf, HID * HID / 4,
      kv_a_w + 64 * HID, qaw_bf + (size_t)2048 * HID, KVR * HID / 4,
      kv_b_w, kvbw_bf, 4096 * KVR / 4,
      o_w, ow_bf, HID * HID / 4);
  yarn_table<<<dim3(S_LEN * 32 / 256), blk, 0, stream>>>(cs_t);

  // fused q-proj (+RoPE, +QSCALE) and kv_a: N = 2048 + 512 = 2560 (640 blocks, %8==0)
  gemm_bt<2><<<dim3(2560 / 128, TOKENS / 128), blk, 0, stream>>>(
      h_bf, qaw_bf, q_bf, lat_f, cs_t, TOKENS, 2560, HID);
  rmsnorm_kernel<<<dim3(TOKENS / 4), blk, 0, stream>>>(lat_f, nw, lat_bf);
  // kv_b: K-part (+RoPE) row-major, V-part direct-transposed to Vt (1024 blocks)
  gemm_bt<3><<<dim3(4096 / 128, TOKENS / 128), blk, 0, stream>>>(
      lat_bf, kvbw_bf, kv_bf, vt_bf, cs_t, TOKENS, 4096, KVR);

  attn_kernel<<<dim3(BATCH * NH, S_LEN / 128), blk, 0, stream>>>(q_bf, kv_bf, vt_bf, attn_bf);

  // o-proj (512 blocks)
  gemm_bt<1><<<dim3(HID / 128, TOKENS / 128), blk, 0, stream>>>(
      attn_bf, ow_bf, (float*)d_out, nullptr, cs_t, TOKENS, HID, HID);
}